// Round 4
// baseline (9136.530 us; speedup 1.0000x reference)
//
#include <hip/hip_runtime.h>

// 2-layer tanh RNN, B=64 T=512 H=512, f32 in/out.
// R11: proven R9 agent-scope tag-in-data protocol (fire-and-forget tagged
// stores, rep-gated self-validating sweeps), with two traffic levers:
// (1) f16 single-pass weights (replaces bf16 hi+lo; h quantization improves
//     2^-8 -> 2^-11, W ~2^-11 vs exact; halves MFMA + A-regs);
// (2) 16 WGs/layer x 512 thr (32 rows/WG, 8 waves = 2 rowgroups x 4
//     colgroups) -> halves sync parties (64 -> 32 WGs).
// Rationale: R7 (flags+barriers) and R9 (tags) both = 9.0us/step despite
// different protocols; FETCH_SIZE ~= sweep volume proves agent-scope sync
// ops are HBM/fabric-class (bypass L1+L2 by coherence necessity). The 9us =
// ~3 fabric RTTs inflated ~6x by coherence-point contention from 64 WGs
// polling. R10's XCD-local L2 attempt FAILED: sc0 store stops in local L2,
// sc0 load bypasses local L2 -> read stale HBM under the dirty line (tag
// period-4 aliasing made it silent). Local-L2 rendezvous needs buffer_inv +
// plain loads (deferred). This round: cut the contention multiplier.
// History (us/step): R7 8.94 | R8 13.5 | R9 8.98 | R10 fail.

#define HD 512
#define BATCH 64
#define SEQ 512
#define NVOCAB 25
#define OUTD 1000
#define NWGL 16           // WGs per layer
#define BH (BATCH * HD)   // 32768 u16 per ring slot
#define BHQ (BH / 4)      // 8192 u64 per ring slot
#define D1 8              // h1 ring depth (layer0 may run <=7 steps ahead)
#define LOGD1 3
#define D2 2              // h2 ring depth (self-synchronized, provably safe)
#define LOGD2 1
#define PSTRIDE 16        // ints per progress slot (64B line, one writer each)
#define IS64_OFF 2048
#define HDR_INTS 4096
#define GUARD_MAX (1L << 21)  // total spin budget per thread (fail-fast)

typedef unsigned short u16;
typedef unsigned int u32;
typedef unsigned long long u64;
typedef __attribute__((ext_vector_type(8))) _Float16 half8;  // 8 f16
typedef __attribute__((ext_vector_type(4))) float f32x4;

union FragU { u16 h[8]; u64 q[2]; half8 v; };

__device__ __forceinline__ u16 f2h(float f) {
    union { _Float16 h; u16 u; } c; c.h = (_Float16)f; return c.u;  // RNE
}
__device__ __forceinline__ u64 ld64a(const u64* p) {
    return __hip_atomic_load((u64*)p, __ATOMIC_RELAXED, __HIP_MEMORY_SCOPE_AGENT);
}
__device__ __forceinline__ void st64a(u64* p, u64 v) {
    __hip_atomic_store(p, v, __ATOMIC_RELAXED, __HIP_MEMORY_SCOPE_AGENT);
}
__device__ __forceinline__ int ld32a(const int* p) {
    return __hip_atomic_load((int*)p, __ATOMIC_RELAXED, __HIP_MEMORY_SCOPE_AGENT);
}
__device__ __forceinline__ u64 pack_tag(const u16 hv[4], u32 tag) {
    return ((u64)(((u32)hv[0] & 0xFFFEu) | tag))
         | ((u64)hv[1] << 16) | ((u64)hv[2] << 32) | ((u64)hv[3] << 48);
}
// rep packet for producer unit u = (g<<1)|rh (16 WGs x 2 rowgroups), at my
// col-group cw: col = cw*16+(u&15); u64 index = col*128 + g*8 + rh*4 + (lane&3)
__device__ __forceinline__ int repidx(int cw, int u, int lane) {
    return (cw * 16 + (u & 15)) * 128 + (u >> 1) * 8 + (u & 1) * 4 + (lane & 3);
}

// hdr ints: prog[128 slots * PSTRIDE] in [0,2048) | is64 @ [2048].
// Rings: slot 0 = zeros (valid h[0], tag 0); slots >=1 = u64 1 (tag 1 =
// mismatch marker for first write, whose tag is 0).
__global__ void init_kernel(int* hdr, u64* h1, u64* h2, const int* x32) {
    long i = (long)blockIdx.x * 256 + threadIdx.x;
    if (i < HDR_INTS) {
        if (i == IS64_OFF) {  // probe x int width: int64 LE => odd words all 0
            int all0 = 1;
            for (int j = 0; j < 64; ++j) if (x32[2 * j + 1] != 0) all0 = 0;
            hdr[i] = all0;
        } else hdr[i] = 0;
    } else {
        long r = i - HDR_INTS;
        if (r < (long)D1 * BHQ) h1[r] = (r < BHQ) ? 0ull : 1ull;
        else {
            long s = r - (long)D1 * BHQ;
            if (s < (long)D2 * BHQ) h2[s] = (s < BHQ) ? 0ull : 1ull;
        }
    }
}

__global__ __launch_bounds__(512, 2) void rnn_fused(
    const float* __restrict__ Whh0, const float* __restrict__ Wih0,
    const int* __restrict__ x,
    const float* __restrict__ bih0, const float* __restrict__ bhh0,
    const float* __restrict__ Whh1, const float* __restrict__ Wih1,
    const float* __restrict__ bih1, const float* __restrict__ bhh1,
    u64* h1ring, u64* h2ring, float* h2final, int* hdr)
{
    int* prog = hdr;  // layer1 wave (g,w) publishes "h1[s] consumed" at g*8+w
    const int tid  = threadIdx.x;
    const int wave = tid >> 6;
    const int lane = tid & 63;
    const int quad = lane >> 4;
    const int l16  = lane & 15;
    const int layer = blockIdx.x >> 4;      // 0 or 1 (16 WGs each)
    const int g  = blockIdx.x & 15;
    const int rh = wave >> 2;               // row-group within WG (0/1)
    const int cw = wave & 3;                // col-group within WG (0..3)
    const int rowbase = g * 32 + rh * 16;   // 16 WGs x 32 rows = 512
    const int arow = rowbase + l16;         // A row (m = lane&15)
    const int row0 = rowbase + quad * 4;    // C/D rows: quad*4 + reg
    const int col  = cw * 16 + l16;         // C/D col (batch)

    __shared__ u16 ldsW[2][16][4][16][8];   // layer1 Wih1 f16 frags, 32 KB

    // Whh as f16, register-resident: A[m=lane&15][k=quad*8+j], 64 VGPRs.
    const float* Wself = layer ? Whh1 : Whh0;
    half8 Ah[16];
    #pragma unroll
    for (int kc = 0; kc < 16; ++kc) {
        FragU th;
        #pragma unroll
        for (int j = 0; j < 8; ++j)
            th.h[j] = f2h(Wself[arow * HD + kc * 32 + quad * 8 + j]);
        Ah[kc] = th.v;
    }
    if (layer == 1 && cw == 0) {  // waves 0 (rh0) and 4 (rh1) fill their block
        #pragma unroll
        for (int kc = 0; kc < 16; ++kc) {
            FragU th;
            #pragma unroll
            for (int j = 0; j < 8; ++j)
                th.h[j] = f2h(Wih1[arow * HD + kc * 32 + quad * 8 + j]);
            *(half8*)&ldsW[rh][kc][quad][l16][0] = th.v;
        }
    }
    const float* bA = layer ? bih1 : bih0;
    const float* bB = layer ? bhh1 : bhh0;
    float bsum[4];
    #pragma unroll
    for (int i = 0; i < 4; ++i) bsum[i] = bA[row0 + i] + bB[row0 + i];
    const int is64 = hdr[IS64_OFF];
    __syncthreads();  // covers LDS init; NO barriers inside the step loop

    long guard = 0;
    int pv = 0;  // layer0: cached layer1 progress for my WAR slot (monotone)

    for (int t = 0; t < SEQ; ++t) {
        if (layer == 0) {
            // x gather + embed row prefetch (read-only, L1/L2-cached);
            // issued before the poll so it's in flight during the wait.
            int xi = is64 ? (int)((const long long*)x)[col * SEQ + t]
                          : x[col * SEQ + t];
            float wx[4];
            #pragma unroll
            for (int i = 0; i < 4; ++i) wx[i] = Wih0[(row0 + i) * NVOCAB + xi];
            // WAR back-channel: my packets (cols cw, rows rh) are read by the
            // 32 layer1 waves with cw'==cw: slots (lane>>1)*8+(lane&1)*4+cw.
            const int need = t + 1 - D1;
            const int wslot = ((lane >> 1) * 8 + (lane & 1) * 4 + cw) * PSTRIDE;
            if (need > 0) {
                bool stale = (lane < 32) && (pv < need);
                if (__ballot(stale) != 0ULL && stale) pv = ld32a(prog + wslot);
            }
            const int sl = t & (D1 - 1);
            const u32 ex = (u32)((t >> LOGD1) & 1);
            const u64* sb = h1ring + (size_t)sl * BHQ;
            // ---- rep poll: one packet per producer wave (8B/lane/iter) ----
            {
                const u64* rep = sb + repidx(cw, lane & 31, lane);
                for (;;) {
                    u32 bad = (((u32)ld64a(rep)) ^ ex) & 1u;
                    if (__ballot(bad != 0) == 0ULL) break;
                    if (++guard > GUARD_MAX) break;
                    __builtin_amdgcn_s_sleep(2);
                }
            }
            // ---- data sweep (self-validating tags; usually 1 iteration) ----
            const u64* pb = sb + (size_t)col * 128 + quad * 2;
            u64 q[32];
            for (;;) {
                #pragma unroll
                for (int kc = 0; kc < 16; ++kc) {
                    q[2 * kc]     = ld64a(pb + kc * 8);
                    q[2 * kc + 1] = ld64a(pb + kc * 8 + 1);
                }
                u32 bad = 0;
                #pragma unroll
                for (int j = 0; j < 32; ++j) bad |= ((u32)q[j] ^ ex) & 1u;
                if (__ballot(bad != 0) == 0ULL) break;
                if (++guard > GUARD_MAX) break;
            }
            // two independent acc chains (kc parity) for MFMA ILP
            f32x4 a0 = {0.f, 0.f, 0.f, 0.f}, a1 = a0;
            #pragma unroll
            for (int kc = 0; kc < 16; kc += 2) {
                FragU f0; f0.q[0] = q[2 * kc];     f0.q[1] = q[2 * kc + 1];
                FragU f1; f1.q[0] = q[2 * kc + 2]; f1.q[1] = q[2 * kc + 3];
                a0 = __builtin_amdgcn_mfma_f32_16x16x32_f16(Ah[kc],     f0.v, a0, 0, 0, 0);
                a1 = __builtin_amdgcn_mfma_f32_16x16x32_f16(Ah[kc + 1], f1.v, a1, 0, 0, 0);
            }
            float hf[4]; u16 hv[4];
            #pragma unroll
            for (int i = 0; i < 4; ++i) {
                float pre = a0[i] + a1[i] + bsum[i] + wx[i];
                hf[i] = tanhf(pre); hv[i] = f2h(hf[i]);
            }
            // blocking WAR check (normally satisfied by the early refresh)
            if (need > 0) {
                while (__ballot((lane < 32) && (pv < need)) != 0ULL) {
                    if ((lane < 32) && (pv < need)) pv = ld32a(prog + wslot);
                    if (++guard > GUARD_MAX) break;
                }
            }
            const int wsl = (t + 1) & (D1 - 1);
            const u32 wtg = (u32)(((t + 1) >> LOGD1) & 1);
            st64a(h1ring + (size_t)wsl * BHQ + col * 128 + (row0 >> 2),
                  pack_tag(hv, wtg));  // fire-and-forget; tag is the flag
        } else {
            const int s2 = t & (D2 - 1);
            const u32 e2 = (u32)((t >> LOGD2) & 1);
            const int s1 = (t + 1) & (D1 - 1);
            const u32 e1 = (u32)(((t + 1) >> LOGD1) & 1);
            const u64* b2 = h2ring + (size_t)s2 * BHQ;
            const u64* b1 = h1ring + (size_t)s1 * BHQ;
            // ---- rep poll: lanes 0-31 watch h2[t], lanes 32-63 h1[t+1] ----
            {
                const u64* rep = (lane < 32) ? (b2 + repidx(cw, lane & 31, lane))
                                             : (b1 + repidx(cw, lane & 31, lane));
                const u32 exr = (lane < 32) ? e2 : e1;
                for (;;) {
                    u32 bad = (((u32)ld64a(rep)) ^ exr) & 1u;
                    if (__ballot(bad != 0) == 0ULL) break;
                    if (++guard > GUARD_MAX) break;
                    __builtin_amdgcn_s_sleep(2);
                }
            }
            // ---- combined data sweep ----
            const u64* pb2 = b2 + (size_t)col * 128 + quad * 2;
            const u64* pb1 = b1 + (size_t)col * 128 + quad * 2;
            u64 q2[32], q1[32];
            for (;;) {
                #pragma unroll
                for (int kc = 0; kc < 16; ++kc) {
                    q2[2 * kc]     = ld64a(pb2 + kc * 8);
                    q2[2 * kc + 1] = ld64a(pb2 + kc * 8 + 1);
                    q1[2 * kc]     = ld64a(pb1 + kc * 8);
                    q1[2 * kc + 1] = ld64a(pb1 + kc * 8 + 1);
                }
                u32 bad = 0;
                #pragma unroll
                for (int j = 0; j < 32; ++j) {
                    bad |= ((u32)q2[j] ^ e2) & 1u;
                    bad |= ((u32)q1[j] ^ e1) & 1u;
                }
                if (__ballot(bad != 0) == 0ULL) break;
                if (++guard > GUARD_MAX) break;
            }
            // publish "h1[t+1] consumed" (ordered after loads via data dep)
            if (lane == 0) {
                int pubv = t + 1;
                u32 dep = (u32)q1[0];
                asm volatile("" : "+v"(pubv) : "v"(dep));
                __hip_atomic_store(prog + (g * 8 + wave) * PSTRIDE, pubv,
                                   __ATOMIC_RELAXED, __HIP_MEMORY_SCOPE_AGENT);
            }
            // four independent acc chains (self/input x kc-parity)
            f32x4 aS0 = {0.f, 0.f, 0.f, 0.f}, aS1 = aS0, aI0 = aS0, aI1 = aS0;
            #pragma unroll
            for (int kc = 0; kc < 16; kc += 2) {
                FragU f2a; f2a.q[0] = q2[2 * kc];     f2a.q[1] = q2[2 * kc + 1];
                FragU f2b; f2b.q[0] = q2[2 * kc + 2]; f2b.q[1] = q2[2 * kc + 3];
                FragU f1a; f1a.q[0] = q1[2 * kc];     f1a.q[1] = q1[2 * kc + 1];
                FragU f1b; f1b.q[0] = q1[2 * kc + 2]; f1b.q[1] = q1[2 * kc + 3];
                half8 w1a = *(half8*)&ldsW[rh][kc][quad][l16][0];
                half8 w1b = *(half8*)&ldsW[rh][kc + 1][quad][l16][0];
                aS0 = __builtin_amdgcn_mfma_f32_16x16x32_f16(Ah[kc],     f2a.v, aS0, 0, 0, 0);
                aS1 = __builtin_amdgcn_mfma_f32_16x16x32_f16(Ah[kc + 1], f2b.v, aS1, 0, 0, 0);
                aI0 = __builtin_amdgcn_mfma_f32_16x16x32_f16(w1a, f1a.v, aI0, 0, 0, 0);
                aI1 = __builtin_amdgcn_mfma_f32_16x16x32_f16(w1b, f1b.v, aI1, 0, 0, 0);
            }
            float hf[4]; u16 hv[4];
            #pragma unroll
            for (int i = 0; i < 4; ++i) {
                float pre = aS0[i] + aS1[i] + aI0[i] + aI1[i] + bsum[i];
                hf[i] = tanhf(pre); hv[i] = f2h(hf[i]);
            }
            const int wsl = (t + 1) & (D2 - 1);
            const u32 wtg = (u32)(((t + 1) >> LOGD2) & 1);
            st64a(h2ring + (size_t)wsl * BHQ + col * 128 + (row0 >> 2),
                  pack_tag(hv, wtg));
            if (t == SEQ - 1)
                *(f32x4*)(h2final + col * HD + row0) = *(f32x4*)hf;  // exact f32
        }
    }
}

__global__ __launch_bounds__(256) void out_kernel(
    const float* __restrict__ h2last, const float* __restrict__ Wout,
    const float* __restrict__ bout, float* __restrict__ out)
{
    int o = blockIdx.x * 256 + threadIdx.x;
    int b = blockIdx.y;
    if (o >= OUTD) return;
    const float* hrow = h2last + b * HD;
    const float* wrow = Wout + o * HD;
    float acc = 0.f;
    for (int k = 0; k < HD; k += 4) {
        float4 hv = *(const float4*)(hrow + k);
        float4 wv = *(const float4*)(wrow + k);
        acc += hv.x * wv.x + hv.y * wv.y + hv.z * wv.z + hv.w * wv.w;
    }
    out[b * OUTD + o] = acc + bout[o];
}

extern "C" void kernel_launch(void* const* d_in, const int* in_sizes, int n_in,
                              void* d_out, int out_size, void* d_ws, size_t ws_size,
                              hipStream_t stream) {
    const int*   x     = (const int*)d_in[0];
    const float* W_ih0 = (const float*)d_in[1];
    const float* W_hh0 = (const float*)d_in[2];
    const float* b_ih0 = (const float*)d_in[3];
    const float* b_hh0 = (const float*)d_in[4];
    const float* W_ih1 = (const float*)d_in[5];
    const float* W_hh1 = (const float*)d_in[6];
    const float* b_ih1 = (const float*)d_in[7];
    const float* b_hh1 = (const float*)d_in[8];
    const float* W_out = (const float*)d_in[9];
    const float* b_out = (const float*)d_in[10];

    // ws: hdr 16KB | h1ring D1*64KB (512KB) | h2ring D2*64KB (128KB) | h2final 128KB
    const size_t needed = (size_t)HDR_INTS * 4 + (size_t)D1 * BHQ * 8
                        + (size_t)D2 * BHQ * 8 + (size_t)BH * 4;  // 802816 B
    if (ws_size < needed) return;  // signature: absmax=0.149 non-NaN => ws short

    int* hdr = (int*)d_ws;
    u64* h1ring = (u64*)((char*)d_ws + (size_t)HDR_INTS * 4);
    u64* h2ring = h1ring + (size_t)D1 * BHQ;
    float* h2final = (float*)(h2ring + (size_t)D2 * BHQ);

    const long ninit = HDR_INTS + (long)(D1 + D2) * BHQ;  // 86016
    init_kernel<<<(int)((ninit + 255) / 256), 256, 0, stream>>>(hdr, h1ring, h2ring, x);
    rnn_fused<<<2 * NWGL, 512, 0, stream>>>(W_hh0, W_ih0, x, b_ih0, b_hh0,
                                            W_hh1, W_ih1, b_ih1, b_hh1,
                                            h1ring, h2ring, h2final, hdr);
    out_kernel<<<dim3(4, BATCH), 256, 0, stream>>>(h2final, W_out, b_out, (float*)d_out);
}

// Round 5
// 2914.558 us; speedup vs baseline: 3.1348x; 3.1348x over previous
//
#include <hip/hip_runtime.h>

// 2-layer tanh RNN, B=64 T=512 H=512, f32 in/out.
// R12 = R9 geometry (64 WGs x 256 thr, 4 waves/CU — best measured) +
// f16 single-pass weights (R11-proven numerics) + 16B dwordx4 sc0 sweeps.
// Model (from R9 vs R11 A/B): step time is dominated by per-CU issue of
// fabric-class (coherent, L1/L2-bypassing) vmem ops: R11 concentrated 2x
// sweep instrs/CU -> 2x step time; 8B load pairs also double-fetched each
// 64B line (no L1 merge). Fix: one global_load_dwordx4 sc0 per 16B fragment
// (contiguous by layout), halving fabric ops AND line fetches. Tag-in-data
// protocol unchanged (per-8B step-parity tag in mantissa LSB; 16B tearing
// harmless — each 8B half self-validates). Rep-gated polls, D1=8 ring with
// lazy WAR back-channel, D2=2 self-safe ring, fire-and-forget stores.
// History (us/step): R7 8.94 | R8 13.5 | R9 8.98 | R10 fail (sc0 store/load
// scope mismatch) | R11 17.5 (2x waves/CU).

#define HD 512
#define BATCH 64
#define SEQ 512
#define NVOCAB 25
#define OUTD 1000
#define NWG 32            // WGs per layer
#define BH (BATCH * HD)   // 32768 u16 per ring slot
#define BHQ (BH / 4)      // 8192 u64 per ring slot
#define D1 8              // h1 ring depth (layer0 may run <=7 steps ahead)
#define LOGD1 3
#define D2 2              // h2 ring depth (self-synchronized, provably safe)
#define LOGD2 1
#define PSTRIDE 16        // ints per progress slot (64B line, one writer each)
#define IS64_OFF 2048
#define HDR_INTS 4096
#define GUARD_MAX (1L << 21)  // total spin budget per thread (fail-fast)

typedef unsigned short u16;
typedef unsigned int u32;
typedef unsigned long long u64;
typedef __attribute__((ext_vector_type(8))) _Float16 half8;   // 8 f16 = 16B
typedef __attribute__((ext_vector_type(4))) u32 u32x4;        // 16B
typedef __attribute__((ext_vector_type(4))) float f32x4;

union Frag16 { u32x4 x; u64 q[2]; u16 h[8]; half8 v; };

__device__ __forceinline__ u16 f2h(float f) {
    union { _Float16 h; u16 u; } c; c.h = (_Float16)f; return c.u;  // RNE
}
__device__ __forceinline__ u64 ld64a(const u64* p) {
    return __hip_atomic_load((u64*)p, __ATOMIC_RELAXED, __HIP_MEMORY_SCOPE_AGENT);
}
__device__ __forceinline__ void st64a(u64* p, u64 v) {
    __hip_atomic_store(p, v, __ATOMIC_RELAXED, __HIP_MEMORY_SCOPE_AGENT);
}
__device__ __forceinline__ int ld32a(const int* p) {
    return __hip_atomic_load((int*)p, __ATOMIC_RELAXED, __HIP_MEMORY_SCOPE_AGENT);
}
// 16B device-coherent load (bypasses L1/L2 like the agent atomics; proven
// read-through semantics in R10). Non-atomic is fine: each 8B half carries
// its own tag and self-validates.
#define LDX4(dst, addr) \
    asm volatile("global_load_dwordx4 %0, %1, off sc0" : "=v"(dst) : "v"(addr))

__device__ __forceinline__ u64 pack_tag(const u16 hv[4], u32 tag) {
    return ((u64)(((u32)hv[0] & 0xFFFEu) | tag))
         | ((u64)hv[1] << 16) | ((u64)hv[2] << 32) | ((u64)hv[3] << 48);
}

// hdr ints: prog[128 slots * PSTRIDE] in [0,2048) | is64 @ [2048].
// Rings: slot 0 = zeros (valid h[0], tag 0); slots >=1 = u64 1 (tag 1 =
// mismatch marker for first write, whose tag is 0).
__global__ void init_kernel(int* hdr, u64* h1, u64* h2, const int* x32) {
    long i = (long)blockIdx.x * 256 + threadIdx.x;
    if (i < HDR_INTS) {
        if (i == IS64_OFF) {  // probe x int width: int64 LE => odd words all 0
            int all0 = 1;
            for (int j = 0; j < 64; ++j) if (x32[2 * j + 1] != 0) all0 = 0;
            hdr[i] = all0;
        } else hdr[i] = 0;
    } else {
        long r = i - HDR_INTS;
        if (r < (long)D1 * BHQ) h1[r] = (r < BHQ) ? 0ull : 1ull;
        else {
            long s = r - (long)D1 * BHQ;
            if (s < (long)D2 * BHQ) h2[s] = (s < BHQ) ? 0ull : 1ull;
        }
    }
}

__global__ __launch_bounds__(256, 1) void rnn_fused(
    const float* __restrict__ Whh0, const float* __restrict__ Wih0,
    const int* __restrict__ x,
    const float* __restrict__ bih0, const float* __restrict__ bhh0,
    const float* __restrict__ Whh1, const float* __restrict__ Wih1,
    const float* __restrict__ bih1, const float* __restrict__ bhh1,
    u64* h1ring, u64* h2ring, float* h2final, int* hdr)
{
    int* prog = hdr;  // layer1 wave (g,w) publishes "h1[s] consumed" at g*4+w
    const int tid  = threadIdx.x;
    const int wave = tid >> 6;
    const int lane = tid & 63;
    const int quad = lane >> 4;
    const int l16  = lane & 15;
    const int layer = blockIdx.x >> 5;          // 0 or 1
    const int g = blockIdx.x & 31;
    const int rowbase = g * 16;                 // 32 WGs x 16 rows = 512
    const int arow = rowbase + l16;             // A row (m = lane&15)
    const int row0 = rowbase + quad * 4;        // C/D rows: quad*4 + reg
    const int col  = wave * 16 + l16;           // C/D col (batch)
    // representative packet offset for producer WG pg, within my col-plane:
    // col = wave*16 + (pg&15), u64 idx = 4*pg + (pg&3)  (rows 16pg+4(pg&3)..+4)
    const int pg = lane & 31;
    const size_t repoff = (size_t)(wave * 16 + (pg & 15)) * 128 + 4 * pg + (pg & 3);

    __shared__ u16 ldsW[16][4][16][8];          // layer1 Wih1 f16 frags, 16 KB

    // Whh as f16, register-resident: A[m=lane&15][k=quad*8+j], 64 VGPRs.
    const float* Wself = layer ? Whh1 : Whh0;
    half8 Ah[16];
    #pragma unroll
    for (int kc = 0; kc < 16; ++kc) {
        Frag16 th;
        #pragma unroll
        for (int j = 0; j < 8; ++j)
            th.h[j] = f2h(Wself[arow * HD + kc * 32 + quad * 8 + j]);
        Ah[kc] = th.v;
    }
    if (layer && wave == 0) {  // all 4 waves share the same A rows
        #pragma unroll
        for (int kc = 0; kc < 16; ++kc) {
            Frag16 th;
            #pragma unroll
            for (int j = 0; j < 8; ++j)
                th.h[j] = f2h(Wih1[arow * HD + kc * 32 + quad * 8 + j]);
            *(half8*)&ldsW[kc][quad][l16][0] = th.v;
        }
    }
    const float* bA = layer ? bih1 : bih0;
    const float* bB = layer ? bhh1 : bhh0;
    float bsum[4];
    #pragma unroll
    for (int i = 0; i < 4; ++i) bsum[i] = bA[row0 + i] + bB[row0 + i];
    const int is64 = hdr[IS64_OFF];
    __syncthreads();  // covers LDS init; NO barriers inside the step loop

    long guard = 0;
    int pv = 0;  // cached layer1 progress (lanes 0..31), monotone

    for (int t = 0; t < SEQ; ++t) {
        if (layer == 0) {
            // x gather + embed row prefetch (read-only, L1/L2-cached);
            // issued before the poll so it's in flight during the wait.
            int xi = is64 ? (int)((const long long*)x)[col * SEQ + t]
                          : x[col * SEQ + t];
            float wx[4];
            #pragma unroll
            for (int i = 0; i < 4; ++i) wx[i] = Wih0[(row0 + i) * NVOCAB + xi];
            // WAR back-channel: refresh early (non-blocking), check before store.
            const int need = t + 1 - D1;  // layer1 must have consumed h1[need]
            if (need > 0) {
                bool stale = (lane < 32) && (pv < need);
                if (__ballot(stale) != 0ULL && stale)
                    pv = ld32a(prog + (lane * 4 + wave) * PSTRIDE);
            }
            const int sl = t & (D1 - 1);
            const u32 ex = (u32)((t >> LOGD1) & 1);
            const u64* sb = h1ring + (size_t)sl * BHQ;
            // ---- rep poll: one packet per producer WG (8B/lane/iter) ----
            {
                const u64* rep = sb + repoff;
                for (;;) {
                    u32 bad = (((u32)ld64a(rep)) ^ ex) & 1u;
                    if (__ballot(bad != 0) == 0ULL) break;
                    if (++guard > GUARD_MAX) break;
                    __builtin_amdgcn_s_sleep(1);
                }
            }
            // ---- data sweep: 16 x dwordx4 (16B contiguous per fragment) ----
            const u64* pb = sb + (size_t)col * 128 + quad * 2;
            Frag16 B[16];
            for (;;) {
                #pragma unroll
                for (int kc = 0; kc < 16; ++kc) LDX4(B[kc].x, pb + kc * 8);
                asm volatile("s_waitcnt vmcnt(0)" ::: "memory");
                __builtin_amdgcn_sched_barrier(0);
                u32 bad = 0;
                #pragma unroll
                for (int kc = 0; kc < 16; ++kc)
                    bad |= ((((u32)B[kc].q[0]) ^ ex) | (((u32)B[kc].q[1]) ^ ex)) & 1u;
                if (__ballot(bad != 0) == 0ULL) break;
                if (++guard > GUARD_MAX) break;
            }
            // two independent acc chains (kc parity) for MFMA ILP
            f32x4 a0 = {0.f, 0.f, 0.f, 0.f}, a1 = a0;
            #pragma unroll
            for (int kc = 0; kc < 16; kc += 2) {
                a0 = __builtin_amdgcn_mfma_f32_16x16x32_f16(Ah[kc],     B[kc].v,     a0, 0, 0, 0);
                a1 = __builtin_amdgcn_mfma_f32_16x16x32_f16(Ah[kc + 1], B[kc + 1].v, a1, 0, 0, 0);
            }
            float hf[4]; u16 hv[4];
            #pragma unroll
            for (int i = 0; i < 4; ++i) {
                float pre = a0[i] + a1[i] + bsum[i] + wx[i];
                hf[i] = tanhf(pre); hv[i] = f2h(hf[i]);
            }
            // blocking WAR check (normally satisfied by the early refresh)
            if (need > 0) {
                while (__ballot((lane < 32) && (pv < need)) != 0ULL) {
                    if ((lane < 32) && (pv < need))
                        pv = ld32a(prog + (lane * 4 + wave) * PSTRIDE);
                    if (++guard > GUARD_MAX) break;
                }
            }
            const int wsl = (t + 1) & (D1 - 1);
            const u32 wtg = (u32)(((t + 1) >> LOGD1) & 1);
            st64a(h1ring + (size_t)wsl * BHQ + col * 128 + (row0 >> 2),
                  pack_tag(hv, wtg));  // fire-and-forget; tag is the flag
        } else {
            const int s2 = t & (D2 - 1);
            const u32 e2 = (u32)((t >> LOGD2) & 1);
            const int s1 = (t + 1) & (D1 - 1);
            const u32 e1 = (u32)(((t + 1) >> LOGD1) & 1);
            const u64* b2 = h2ring + (size_t)s2 * BHQ;
            const u64* b1 = h1ring + (size_t)s1 * BHQ;
            // ---- rep poll: lanes 0-31 watch h2[t], lanes 32-63 h1[t+1] ----
            {
                const u64* rep = (lane < 32) ? (b2 + repoff) : (b1 + repoff);
                const u32 exr = (lane < 32) ? e2 : e1;
                for (;;) {
                    u32 bad = (((u32)ld64a(rep)) ^ exr) & 1u;
                    if (__ballot(bad != 0) == 0ULL) break;
                    if (++guard > GUARD_MAX) break;
                    __builtin_amdgcn_s_sleep(1);
                }
            }
            // ---- combined data sweep: 32 x dwordx4 ----
            const u64* pb2 = b2 + (size_t)col * 128 + quad * 2;
            const u64* pb1 = b1 + (size_t)col * 128 + quad * 2;
            Frag16 B2[16], B1[16];
            for (;;) {
                #pragma unroll
                for (int kc = 0; kc < 16; ++kc) {
                    LDX4(B2[kc].x, pb2 + kc * 8);
                    LDX4(B1[kc].x, pb1 + kc * 8);
                }
                asm volatile("s_waitcnt vmcnt(0)" ::: "memory");
                __builtin_amdgcn_sched_barrier(0);
                u32 bad = 0;
                #pragma unroll
                for (int kc = 0; kc < 16; ++kc) {
                    bad |= ((((u32)B2[kc].q[0]) ^ e2) | (((u32)B2[kc].q[1]) ^ e2)) & 1u;
                    bad |= ((((u32)B1[kc].q[0]) ^ e1) | (((u32)B1[kc].q[1]) ^ e1)) & 1u;
                }
                if (__ballot(bad != 0) == 0ULL) break;
                if (++guard > GUARD_MAX) break;
            }
            // publish "h1[t+1] consumed" (ordered after loads via data dep)
            if (lane == 0) {
                int pubv = t + 1;
                u32 dep = (u32)B1[0].q[0];
                asm volatile("" : "+v"(pubv) : "v"(dep));
                __hip_atomic_store(prog + (g * 4 + wave) * PSTRIDE, pubv,
                                   __ATOMIC_RELAXED, __HIP_MEMORY_SCOPE_AGENT);
            }
            // four independent acc chains (self/input x kc-parity)
            f32x4 aS0 = {0.f, 0.f, 0.f, 0.f}, aS1 = aS0, aI0 = aS0, aI1 = aS0;
            #pragma unroll
            for (int kc = 0; kc < 16; kc += 2) {
                half8 w1a = *(half8*)&ldsW[kc][quad][l16][0];
                half8 w1b = *(half8*)&ldsW[kc + 1][quad][l16][0];
                aS0 = __builtin_amdgcn_mfma_f32_16x16x32_f16(Ah[kc],     B2[kc].v,     aS0, 0, 0, 0);
                aS1 = __builtin_amdgcn_mfma_f32_16x16x32_f16(Ah[kc + 1], B2[kc + 1].v, aS1, 0, 0, 0);
                aI0 = __builtin_amdgcn_mfma_f32_16x16x32_f16(w1a, B1[kc].v,     aI0, 0, 0, 0);
                aI1 = __builtin_amdgcn_mfma_f32_16x16x32_f16(w1b, B1[kc + 1].v, aI1, 0, 0, 0);
            }
            float hf[4]; u16 hv[4];
            #pragma unroll
            for (int i = 0; i < 4; ++i) {
                float pre = aS0[i] + aS1[i] + aI0[i] + aI1[i] + bsum[i];
                hf[i] = tanhf(pre); hv[i] = f2h(hf[i]);
            }
            const int wsl = (t + 1) & (D2 - 1);
            const u32 wtg = (u32)(((t + 1) >> LOGD2) & 1);
            st64a(h2ring + (size_t)wsl * BHQ + col * 128 + (row0 >> 2),
                  pack_tag(hv, wtg));
            if (t == SEQ - 1)
                *(f32x4*)(h2final + col * HD + row0) = *(f32x4*)hf;  // exact f32
        }
    }
}

__global__ __launch_bounds__(256) void out_kernel(
    const float* __restrict__ h2last, const float* __restrict__ Wout,
    const float* __restrict__ bout, float* __restrict__ out)
{
    int o = blockIdx.x * 256 + threadIdx.x;
    int b = blockIdx.y;
    if (o >= OUTD) return;
    const float* hrow = h2last + b * HD;
    const float* wrow = Wout + o * HD;
    float acc = 0.f;
    for (int k = 0; k < HD; k += 4) {
        float4 hv = *(const float4*)(hrow + k);
        float4 wv = *(const float4*)(wrow + k);
        acc += hv.x * wv.x + hv.y * wv.y + hv.z * wv.z + hv.w * wv.w;
    }
    out[b * OUTD + o] = acc + bout[o];
}

extern "C" void kernel_launch(void* const* d_in, const int* in_sizes, int n_in,
                              void* d_out, int out_size, void* d_ws, size_t ws_size,
                              hipStream_t stream) {
    const int*   x     = (const int*)d_in[0];
    const float* W_ih0 = (const float*)d_in[1];
    const float* W_hh0 = (const float*)d_in[2];
    const float* b_ih0 = (const float*)d_in[3];
    const float* b_hh0 = (const float*)d_in[4];
    const float* W_ih1 = (const float*)d_in[5];
    const float* W_hh1 = (const float*)d_in[6];
    const float* b_ih1 = (const float*)d_in[7];
    const float* b_hh1 = (const float*)d_in[8];
    const float* W_out = (const float*)d_in[9];
    const float* b_out = (const float*)d_in[10];

    // ws: hdr 16KB | h1ring D1*64KB (512KB) | h2ring D2*64KB (128KB) | h2final 128KB
    const size_t needed = (size_t)HDR_INTS * 4 + (size_t)D1 * BHQ * 8
                        + (size_t)D2 * BHQ * 8 + (size_t)BH * 4;  // 802816 B
    if (ws_size < needed) return;  // signature: absmax=0.149 non-NaN => ws short

    int* hdr = (int*)d_ws;
    u64* h1ring = (u64*)((char*)d_ws + (size_t)HDR_INTS * 4);
    u64* h2ring = h1ring + (size_t)D1 * BHQ;
    float* h2final = (float*)(h2ring + (size_t)D2 * BHQ);

    const long ninit = HDR_INTS + (long)(D1 + D2) * BHQ;  // 86016
    init_kernel<<<(int)((ninit + 255) / 256), 256, 0, stream>>>(hdr, h1ring, h2ring, x);
    rnn_fused<<<2 * NWG, 256, 0, stream>>>(W_hh0, W_ih0, x, b_ih0, b_hh0,
                                           W_hh1, W_ih1, b_ih1, b_hh1,
                                           h1ring, h2ring, h2final, hdr);
    out_kernel<<<dim3(4, BATCH), 256, 0, stream>>>(h2final, W_out, b_out, (float*)d_out);
}

// Round 8
// 2080.414 us; speedup vs baseline: 4.3917x; 1.4010x over previous
//
#include <hip/hip_runtime.h>

// 2-layer tanh RNN, B=64 T=512 H=512, f32 in/out.
// R15: R12's EXACT per-wave program (rep-gated poll + self-validating 16B
// sc0 sweeps + fire-and-forget tagged stores, f16 single-pass weights,
// D1=8 ring + lazy WAR back-channel, D2=2 self-safe ring, no in-loop
// barriers) re-packed as 128 WGs x 128 thr: each of the 256 waves is an
// independent 16row x 16col tile (row-unit u = rbig*2 + wv, col-group cg).
// Same total waves/instructions over ~2x the CUs -> per-CU coherent-vmem
// instrs halve (model: step_us ~= 1.7 + 0.028*instrs/CU; fits R9/R11/R12).
// Wih1 register-resident (no LDS, no barriers). Sync domains per-cg
// (fan-in 32 units = same as R12). Guard raised to 2^23 so scheduler
// storms drain rather than corrupt.
// DISCIPLINE (R13/R14 lesson): both failures bundled unproven primitives
// (imm-offset sc0 loads, LDS handoff of sync data, per-thread chunk spin).
// R15 uses ONLY R12-proven primitives; one structural variable (packing).
// History (us/step): R7 8.94 | R8 13.5 | R9 8.98 | R10 fail | R11 17.5 |
// R12 5.55 | R13 fail | R14 fail.

#define HD 512
#define BATCH 64
#define SEQ 512
#define NVOCAB 25
#define OUTD 1000
#define BH (BATCH * HD)   // 32768 u16 per ring slot
#define BHQ (BH / 4)      // 8192 u64 per ring slot
#define D1 8              // h1 ring depth (layer0 may run <=7 steps ahead)
#define LOGD1 3
#define D2 2              // h2 ring depth (self-synchronized, provably safe)
#define LOGD2 1
#define PSTRIDE 16        // ints per progress slot (64B line, one writer each)
#define IS64_OFF 2048
#define HDR_INTS 4096
#define GUARD_MAX (1L << 23)  // spin budget (drain storms, fail-fast on bug)

typedef unsigned short u16;
typedef unsigned int u32;
typedef unsigned long long u64;
typedef __attribute__((ext_vector_type(8))) _Float16 half8;   // 8 f16 = 16B
typedef __attribute__((ext_vector_type(4))) u32 u32x4;        // 16B
typedef __attribute__((ext_vector_type(4))) float f32x4;

union Frag16 { u32x4 x; u64 q[2]; u16 h[8]; half8 v; };

__device__ __forceinline__ u16 f2h(float f) {
    union { _Float16 h; u16 u; } c; c.h = (_Float16)f; return c.u;  // RNE
}
__device__ __forceinline__ u64 ld64a(const u64* p) {
    return __hip_atomic_load((u64*)p, __ATOMIC_RELAXED, __HIP_MEMORY_SCOPE_AGENT);
}
__device__ __forceinline__ void st64a(u64* p, u64 v) {
    __hip_atomic_store(p, v, __ATOMIC_RELAXED, __HIP_MEMORY_SCOPE_AGENT);
}
__device__ __forceinline__ int ld32a(const int* p) {
    return __hip_atomic_load((int*)p, __ATOMIC_RELAXED, __HIP_MEMORY_SCOPE_AGENT);
}
// 16B device-coherent load, computed address (R12-proven form; NO imm offset).
// Non-atomic OK: each 8B half carries its own tag and self-validates.
#define LDX4(dst, addr) \
    asm volatile("global_load_dwordx4 %0, %1, off sc0" : "=v"(dst) : "v"(addr))
#define WAITV0() do { \
    asm volatile("s_waitcnt vmcnt(0)" ::: "memory"); \
    __builtin_amdgcn_sched_barrier(0); \
} while (0)

__device__ __forceinline__ u64 pack_tag(const u16 hv[4], u32 tag) {
    return ((u64)(((u32)hv[0] & 0xFFFEu) | tag))
         | ((u64)hv[1] << 16) | ((u64)hv[2] << 32) | ((u64)hv[3] << 48);
}

// hdr ints: prog[128 slots * PSTRIDE] in [0,2048) | is64 @ [2048].
// Rings: slot 0 = zeros (valid h[0], tag 0); slots >=1 = u64 1 (tag 1 =
// mismatch marker for first write, whose tag is 0). Layout identical to R12.
__global__ void init_kernel(int* hdr, u64* h1, u64* h2, const int* x32) {
    long i = (long)blockIdx.x * 256 + threadIdx.x;
    if (i < HDR_INTS) {
        if (i == IS64_OFF) {  // probe x int width: int64 LE => odd words all 0
            int all0 = 1;
            for (int j = 0; j < 64; ++j) if (x32[2 * j + 1] != 0) all0 = 0;
            hdr[i] = all0;
        } else hdr[i] = 0;
    } else {
        long r = i - HDR_INTS;
        if (r < (long)D1 * BHQ) h1[r] = (r < BHQ) ? 0ull : 1ull;
        else {
            long s = r - (long)D1 * BHQ;
            if (s < (long)D2 * BHQ) h2[s] = (s < BHQ) ? 0ull : 1ull;
        }
    }
}

__global__ __launch_bounds__(128, 1) void rnn_fused(
    const float* __restrict__ Whh0, const float* __restrict__ Wih0,
    const int* __restrict__ x,
    const float* __restrict__ bih0, const float* __restrict__ bhh0,
    const float* __restrict__ Whh1, const float* __restrict__ Wih1,
    const float* __restrict__ bih1, const float* __restrict__ bhh1,
    u64* h1ring, u64* h2ring, float* h2final, int* hdr)
{
    int* prog = hdr;  // L1 wave-unit (cg,u) publishes "h1[s] consumed" at cg*32+u
    const int tid  = threadIdx.x;
    const int wv   = tid >> 6;                  // wave in WG (0/1)
    const int lane = tid & 63;
    const int quad = lane >> 4;
    const int l16  = lane & 15;
    const int layer = blockIdx.x >> 6;          // 0 or 1 (64 WGs each)
    const int w     = blockIdx.x & 63;
    const int rbig  = w >> 2;                   // 0..15 (32-row block)
    const int cg    = w & 3;                    // col-group 0..3 (16 cols)
    const int u     = rbig * 2 + wv;            // row-unit 0..31 (16 rows)
    const int rowbase = u * 16;
    const int arow = rowbase + l16;             // A row (m = lane&15)
    const int row0 = rowbase + quad * 4;        // C/D rows: quad*4 + reg
    const int col  = cg * 16 + l16;             // C/D col (batch)
    // rep packet of producer unit pg (32 row-units of my cg domain): one 8B
    // packet at col cg*16+(pg&15), u64 idx pg*4 + (pg&3) within that col.
    const int pg = lane & 31;
    const size_t repoff = (size_t)(cg * 16 + (pg & 15)) * 128 + pg * 4 + (pg & 3);

    // Whh as f16, register-resident: A[m=lane&15][k=kc*32+quad*8+j], 64 VGPRs.
    const float* Wself = layer ? Whh1 : Whh0;
    half8 Ah[16];
    #pragma unroll
    for (int kc = 0; kc < 16; ++kc) {
        Frag16 th;
        #pragma unroll
        for (int j = 0; j < 8; ++j)
            th.h[j] = f2h(Wself[arow * HD + kc * 32 + quad * 8 + j]);
        Ah[kc] = th.v;
    }
    half8 Aw[16];  // layer1: Wih1 frags, register-resident (64 VGPRs)
    if (layer) {
        #pragma unroll
        for (int kc = 0; kc < 16; ++kc) {
            Frag16 th;
            #pragma unroll
            for (int j = 0; j < 8; ++j)
                th.h[j] = f2h(Wih1[arow * HD + kc * 32 + quad * 8 + j]);
            Aw[kc] = th.v;
        }
    }
    const float* bA = layer ? bih1 : bih0;
    const float* bB = layer ? bhh1 : bhh0;
    float bsum[4];
    #pragma unroll
    for (int i = 0; i < 4; ++i) bsum[i] = bA[row0 + i] + bB[row0 + i];
    const int is64 = hdr[IS64_OFF];

    long guard = 0;
    int pv = 0;  // L0 lanes 0..31: cached L1-unit progress (monotone)

    for (int t = 0; t < SEQ; ++t) {
        if (layer == 0) {
            // x gather + embed row prefetch (read-only, cached); in flight
            // during the poll.
            int xi = is64 ? (int)((const long long*)x)[col * SEQ + t]
                          : x[col * SEQ + t];
            float wx[4];
            #pragma unroll
            for (int i = 0; i < 4; ++i) wx[i] = Wih0[(row0 + i) * NVOCAB + xi];
            // WAR back-channel: refresh early (non-blocking), check pre-store.
            const int need = t + 1 - D1;  // L1 units must have consumed h1[need]
            if (need > 0) {
                bool stale = (lane < 32) && (pv < need);
                if (__ballot(stale) != 0ULL && stale)
                    pv = ld32a(prog + (cg * 32 + lane) * PSTRIDE);
            }
            const int sl = t & (D1 - 1);
            const u32 ex = (u32)((t >> LOGD1) & 1);
            const u64* sb = h1ring + (size_t)sl * BHQ;
            // ---- rep poll: one packet per producer unit (8B/lane/iter) ----
            {
                const u64* rep = sb + repoff;
                for (;;) {
                    u32 bad = (((u32)ld64a(rep)) ^ ex) & 1u;
                    if (__ballot(bad != 0) == 0ULL) break;
                    if (++guard > GUARD_MAX) break;
                    __builtin_amdgcn_s_sleep(1);
                }
            }
            // ---- data sweep: 16 x dwordx4 (16B contiguous per fragment) ----
            const u64* pb = sb + (size_t)col * 128 + quad * 2;
            Frag16 B[16];
            for (;;) {
                #pragma unroll
                for (int kc = 0; kc < 16; ++kc) LDX4(B[kc].x, pb + kc * 8);
                WAITV0();
                u32 bad = 0;
                #pragma unroll
                for (int kc = 0; kc < 16; ++kc)
                    bad |= ((((u32)B[kc].q[0]) ^ ex) | (((u32)B[kc].q[1]) ^ ex)) & 1u;
                if (__ballot(bad != 0) == 0ULL) break;
                if (++guard > GUARD_MAX) break;
            }
            // two independent acc chains (kc parity) for MFMA ILP
            f32x4 a0 = {0.f, 0.f, 0.f, 0.f}, a1 = a0;
            #pragma unroll
            for (int kc = 0; kc < 16; kc += 2) {
                a0 = __builtin_amdgcn_mfma_f32_16x16x32_f16(Ah[kc],     B[kc].v,     a0, 0, 0, 0);
                a1 = __builtin_amdgcn_mfma_f32_16x16x32_f16(Ah[kc + 1], B[kc + 1].v, a1, 0, 0, 0);
            }
            float hf[4]; u16 hv[4];
            #pragma unroll
            for (int i = 0; i < 4; ++i) {
                float pre = a0[i] + a1[i] + bsum[i] + wx[i];
                hf[i] = tanhf(pre); hv[i] = f2h(hf[i]);
            }
            // blocking WAR check (normally satisfied by the early refresh)
            if (need > 0) {
                while (__ballot((lane < 32) && (pv < need)) != 0ULL) {
                    if ((lane < 32) && (pv < need))
                        pv = ld32a(prog + (cg * 32 + lane) * PSTRIDE);
                    if (++guard > GUARD_MAX) break;
                }
            }
            const int wsl = (t + 1) & (D1 - 1);
            const u32 wtg = (u32)(((t + 1) >> LOGD1) & 1);
            st64a(h1ring + (size_t)wsl * BHQ + col * 128 + (row0 >> 2),
                  pack_tag(hv, wtg));  // fire-and-forget; tag is the flag
        } else {
            const int s2 = t & (D2 - 1);
            const u32 e2 = (u32)((t >> LOGD2) & 1);
            const int s1 = (t + 1) & (D1 - 1);
            const u32 e1 = (u32)(((t + 1) >> LOGD1) & 1);
            const u64* b2 = h2ring + (size_t)s2 * BHQ;
            const u64* b1 = h1ring + (size_t)s1 * BHQ;
            // ---- rep poll: lanes 0-31 watch h2[t], lanes 32-63 h1[t+1] ----
            {
                const u64* rep = (lane < 32) ? (b2 + repoff) : (b1 + repoff);
                const u32 exr = (lane < 32) ? e2 : e1;
                for (;;) {
                    u32 bad = (((u32)ld64a(rep)) ^ exr) & 1u;
                    if (__ballot(bad != 0) == 0ULL) break;
                    if (++guard > GUARD_MAX) break;
                    __builtin_amdgcn_s_sleep(1);
                }
            }
            // ---- combined data sweep: 32 x dwordx4 ----
            const u64* pb2 = b2 + (size_t)col * 128 + quad * 2;
            const u64* pb1 = b1 + (size_t)col * 128 + quad * 2;
            Frag16 B2[16], B1[16];
            for (;;) {
                #pragma unroll
                for (int kc = 0; kc < 16; ++kc) {
                    LDX4(B2[kc].x, pb2 + kc * 8);
                    LDX4(B1[kc].x, pb1 + kc * 8);
                }
                WAITV0();
                u32 bad = 0;
                #pragma unroll
                for (int kc = 0; kc < 16; ++kc) {
                    bad |= ((((u32)B2[kc].q[0]) ^ e2) | (((u32)B2[kc].q[1]) ^ e2)) & 1u;
                    bad |= ((((u32)B1[kc].q[0]) ^ e1) | (((u32)B1[kc].q[1]) ^ e1)) & 1u;
                }
                if (__ballot(bad != 0) == 0ULL) break;
                if (++guard > GUARD_MAX) break;
            }
            // publish "h1[t+1] consumed" (ordered after loads via data dep)
            if (lane == 0) {
                int pubv = t + 1;
                u32 dep = (u32)B1[0].q[0];
                asm volatile("" : "+v"(pubv) : "v"(dep));
                __hip_atomic_store(prog + (cg * 32 + u) * PSTRIDE, pubv,
                                   __ATOMIC_RELAXED, __HIP_MEMORY_SCOPE_AGENT);
            }
            // four independent acc chains (self/input x kc-parity)
            f32x4 aS0 = {0.f, 0.f, 0.f, 0.f}, aS1 = aS0, aI0 = aS0, aI1 = aS0;
            #pragma unroll
            for (int kc = 0; kc < 16; kc += 2) {
                aS0 = __builtin_amdgcn_mfma_f32_16x16x32_f16(Ah[kc],     B2[kc].v,     aS0, 0, 0, 0);
                aS1 = __builtin_amdgcn_mfma_f32_16x16x32_f16(Ah[kc + 1], B2[kc + 1].v, aS1, 0, 0, 0);
                aI0 = __builtin_amdgcn_mfma_f32_16x16x32_f16(Aw[kc],     B1[kc].v,     aI0, 0, 0, 0);
                aI1 = __builtin_amdgcn_mfma_f32_16x16x32_f16(Aw[kc + 1], B1[kc + 1].v, aI1, 0, 0, 0);
            }
            float hf[4]; u16 hv[4];
            #pragma unroll
            for (int i = 0; i < 4; ++i) {
                float pre = aS0[i] + aS1[i] + aI0[i] + aI1[i] + bsum[i];
                hf[i] = tanhf(pre); hv[i] = f2h(hf[i]);
            }
            const int wsl = (t + 1) & (D2 - 1);
            const u32 wtg = (u32)(((t + 1) >> LOGD2) & 1);
            st64a(h2ring + (size_t)wsl * BHQ + col * 128 + (row0 >> 2),
                  pack_tag(hv, wtg));
            if (t == SEQ - 1)
                *(f32x4*)(h2final + col * HD + row0) = *(f32x4*)hf;  // exact f32
        }
    }
}

__global__ __launch_bounds__(256) void out_kernel(
    const float* __restrict__ h2last, const float* __restrict__ Wout,
    const float* __restrict__ bout, float* __restrict__ out)
{
    int o = blockIdx.x * 256 + threadIdx.x;
    int b = blockIdx.y;
    if (o >= OUTD) return;
    const float* hrow = h2last + b * HD;
    const float* wrow = Wout + o * HD;
    float acc = 0.f;
    for (int k = 0; k < HD; k += 4) {
        float4 hv = *(const float4*)(hrow + k);
        float4 wv = *(const float4*)(wrow + k);
        acc += hv.x * wv.x + hv.y * wv.y + hv.z * wv.z + hv.w * wv.w;
    }
    out[b * OUTD + o] = acc + bout[o];
}

extern "C" void kernel_launch(void* const* d_in, const int* in_sizes, int n_in,
                              void* d_out, int out_size, void* d_ws, size_t ws_size,
                              hipStream_t stream) {
    const int*   x     = (const int*)d_in[0];
    const float* W_ih0 = (const float*)d_in[1];
    const float* W_hh0 = (const float*)d_in[2];
    const float* b_ih0 = (const float*)d_in[3];
    const float* b_hh0 = (const float*)d_in[4];
    const float* W_ih1 = (const float*)d_in[5];
    const float* W_hh1 = (const float*)d_in[6];
    const float* b_ih1 = (const float*)d_in[7];
    const float* b_hh1 = (const float*)d_in[8];
    const float* W_out = (const float*)d_in[9];
    const float* b_out = (const float*)d_in[10];

    // ws: hdr 16KB | h1ring D1*64KB | h2ring D2*64KB | h2final 128KB (as R12)
    const size_t needed = (size_t)HDR_INTS * 4 + (size_t)D1 * BHQ * 8
                        + (size_t)D2 * BHQ * 8 + (size_t)BH * 4;  // 802816 B
    if (ws_size < needed) return;  // signature: absmax=0.149 non-NaN => ws short

    int* hdr = (int*)d_ws;
    u64* h1ring = (u64*)((char*)d_ws + (size_t)HDR_INTS * 4);
    u64* h2ring = h1ring + (size_t)D1 * BHQ;
    float* h2final = (float*)(h2ring + (size_t)D2 * BHQ);

    const long ninit = HDR_INTS + (long)(D1 + D2) * BHQ;  // 86016
    init_kernel<<<(int)((ninit + 255) / 256), 256, 0, stream>>>(hdr, h1ring, h2ring, x);
    rnn_fused<<<128, 128, 0, stream>>>(W_hh0, W_ih0, x, b_ih0, b_hh0,
                                       W_hh1, W_ih1, b_ih1, b_hh1,
                                       h1ring, h2ring, h2final, hdr);
    out_kernel<<<dim3(4, BATCH), 256, 0, stream>>>(h2final, W_out, b_out, (float*)d_out);
}

// Round 9
// 1840.862 us; speedup vs baseline: 4.9632x; 1.1301x over previous
//
#include <hip/hip_runtime.h>

// 2-layer tanh RNN, B=64 T=512 H=512, f32 in/out.
// R16: MERGED LAYERS. One wave owns rows [u*16,u*16+16) of BOTH h1 and h2
// for its col-group: per step t it computes h1[t] (= tanh(Whh0*h1[t-1]+wx))
// AND h2[t-1] (= tanh(Whh1*h2[t-2] + Wih1*h1[t-1] + b)) from ONE h1 sweep +
// one h2 sweep. 128 waves total (32 row-units x 4 independent col-domains),
// 128 WGs x 64 thr = 1 wave/CU over half the chip. Per-CU coherent ops ~35
// (model from R9/R11/R12/R15: step_us ~= 1.7 + 0.028*ops/CU -> ~2.7us).
// Producer set == consumer set for both rings => BOTH rings are depth-2
// self-safe (store is data-dependent on that step's validated sweep, so
// "slot fully tagged" => "all units finished the prior read") — the D1=8
// ring, WAR back-channel and prog array are gone. Epilogue step t=SEQ
// produces h2[511] -> h2final. Primitives are all R12/R15-proven: rep-gated
// poll, computed-address dwordx4 sc0 sweeps, tag-in-data (parity in mantissa
// LSB per 8B packet), fire-and-forget relaxed-atomic stores, s_sleep backoff,
// bounded spins. Tags: h1 read (t>>1)&1 write ((t+1)>>1)&1, init {0,1};
// h2 read ((t+2)>>1)&1 write ((t+3)>>1)&1, init {1,1} (slot1 = valid
// h2[-1]~=0 tag 1; denormal 6e-8 negligible). Hand-checked t=0..4 + epilogue.
// History (us/step): R7 8.94 | R8 13.5 | R9 8.98 | R10 fail | R11 17.5 |
// R12 5.55 | R13 fail | R14 fail | R15 3.91.

#define HD 512
#define BATCH 64
#define SEQ 512
#define NVOCAB 25
#define OUTD 1000
#define BH (BATCH * HD)   // 32768 u16 per ring slot
#define BHQ (BH / 4)      // 8192 u64 per ring slot
#define IS64_OFF 2048
#define HDR_INTS 4096
#define GUARD_MAX (1L << 23)  // spin budget (drain storms, fail-fast on bug)

typedef unsigned short u16;
typedef unsigned int u32;
typedef unsigned long long u64;
typedef __attribute__((ext_vector_type(8))) _Float16 half8;   // 8 f16 = 16B
typedef __attribute__((ext_vector_type(4))) u32 u32x4;        // 16B
typedef __attribute__((ext_vector_type(4))) float f32x4;

union Frag16 { u32x4 x; u64 q[2]; u16 h[8]; half8 v; };

__device__ __forceinline__ u16 f2h(float f) {
    union { _Float16 h; u16 u; } c; c.h = (_Float16)f; return c.u;  // RNE
}
__device__ __forceinline__ u64 ld64a(const u64* p) {
    return __hip_atomic_load((u64*)p, __ATOMIC_RELAXED, __HIP_MEMORY_SCOPE_AGENT);
}
__device__ __forceinline__ void st64a(u64* p, u64 v) {
    __hip_atomic_store(p, v, __ATOMIC_RELAXED, __HIP_MEMORY_SCOPE_AGENT);
}
// 16B device-coherent load, computed address (R12/R15-proven form).
// Non-atomic OK: each 8B half carries its own tag and self-validates.
#define LDX4(dst, addr) \
    asm volatile("global_load_dwordx4 %0, %1, off sc0" : "=v"(dst) : "v"(addr))
#define WAITV0() do { \
    asm volatile("s_waitcnt vmcnt(0)" ::: "memory"); \
    __builtin_amdgcn_sched_barrier(0); \
} while (0)

__device__ __forceinline__ u64 pack_tag(const u16 hv[4], u32 tag) {
    return ((u64)(((u32)hv[0] & 0xFFFEu) | tag))
         | ((u64)hv[1] << 16) | ((u64)hv[2] << 32) | ((u64)hv[3] << 48);
}

// hdr ints: is64 @ [2048] (rest unused). Rings (u64 space after hdr):
// h1[2*BHQ]: slot0 = 0 (valid h1[0]=0, tag 0), slot1 = 1 (poison tag 1);
// h2[2*BHQ]: slot0 = 1 (poison for h2[-2] read: expect tag 1, data~0, VALID
//            as h2[-2]=0), slot1 = 1 (valid h2[-1]=0, tag 1).
__global__ void init_kernel(int* hdr, u64* h1, u64* h2, const int* x32) {
    long i = (long)blockIdx.x * 256 + threadIdx.x;
    if (i < HDR_INTS) {
        if (i == IS64_OFF) {  // probe x int width: int64 LE => odd words all 0
            int all0 = 1;
            for (int j = 0; j < 64; ++j) if (x32[2 * j + 1] != 0) all0 = 0;
            hdr[i] = all0;
        } else hdr[i] = 0;
    } else {
        long r = i - HDR_INTS;
        if (r < 2L * BHQ) h1[r] = (r < BHQ) ? 0ull : 1ull;
        else if (r < 4L * BHQ) h2[r - 2L * BHQ] = 1ull;
    }
}

__global__ __launch_bounds__(64, 1) void rnn_fused(
    const float* __restrict__ Whh0, const float* __restrict__ Wih0,
    const int* __restrict__ x,
    const float* __restrict__ bih0, const float* __restrict__ bhh0,
    const float* __restrict__ Whh1, const float* __restrict__ Wih1,
    const float* __restrict__ bih1, const float* __restrict__ bhh1,
    u64* h1ring, u64* h2ring, float* h2final, int* hdr)
{
    const int lane = threadIdx.x & 63;
    const int quad = lane >> 4;
    const int l16  = lane & 15;
    const int u    = (int)blockIdx.x >> 2;      // row-unit 0..31 (16 rows)
    const int cg   = (int)blockIdx.x & 3;       // col-group 0..3 (16 cols)
    const int rowbase = u * 16;
    const int arow = rowbase + l16;             // A row (m = lane&15)
    const int row0 = rowbase + quad * 4;        // C/D rows: quad*4 + reg
    const int col  = cg * 16 + l16;             // C/D col (batch)
    // rep packet of producer unit pg (32 row-units of my cg domain): one 8B
    // packet at col cg*16+(pg&15), u64 idx pg*4+(pg&3) (row pg*16+4*(pg&3)).
    const int pg = lane & 31;
    const size_t repoff = (size_t)(cg * 16 + (pg & 15)) * 128 + pg * 4 + (pg & 3);

    // Three weight sets, f16 frags, register-resident:
    // A[m=lane&15][k=kc*32+quad*8+j], 64 VGPRs each.
    half8 A0[16], A1[16], Aw[16];
    #pragma unroll
    for (int kc = 0; kc < 16; ++kc) {
        Frag16 t0, t1, tw;
        #pragma unroll
        for (int j = 0; j < 8; ++j) {
            const int widx = arow * HD + kc * 32 + quad * 8 + j;
            t0.h[j] = f2h(Whh0[widx]);
            t1.h[j] = f2h(Whh1[widx]);
            tw.h[j] = f2h(Wih1[widx]);
        }
        A0[kc] = t0.v; A1[kc] = t1.v; Aw[kc] = tw.v;
    }
    float bs0[4], bs1[4];
    #pragma unroll
    for (int i = 0; i < 4; ++i) {
        bs0[i] = bih0[row0 + i] + bhh0[row0 + i];
        bs1[i] = bih1[row0 + i] + bhh1[row0 + i];
    }
    const int is64 = hdr[IS64_OFF];

    long guard = 0;

    for (int t = 0; t <= SEQ; ++t) {
        // x gather + embed row prefetch (read-only, cached); issued before
        // the poll so it's in flight during the wait. tt clamps the epilogue.
        const int tt = (t < SEQ) ? t : (SEQ - 1);
        int xi = is64 ? (int)((const long long*)x)[col * SEQ + tt]
                      : x[col * SEQ + tt];
        float wx[4];
        #pragma unroll
        for (int i = 0; i < 4; ++i) wx[i] = Wih0[(row0 + i) * NVOCAB + xi];

        const int rs = t & 1;                       // read slot, both rings
        const u32 e1 = (u32)((t >> 1) & 1);         // h1[t-1] state tag
        const u32 e2 = (u32)(((t + 2) >> 1) & 1);   // h2[t-2] state tag
        const u64* sb1 = h1ring + (size_t)rs * BHQ;
        const u64* sb2 = h2ring + (size_t)rs * BHQ;
        // ---- rep poll: lanes 0-31 watch h1, lanes 32-63 watch h2 ----
        {
            const u64* rep = (lane < 32) ? (sb1 + repoff) : (sb2 + repoff);
            const u32 exr = (lane < 32) ? e1 : e2;
            for (;;) {
                u32 bad = (((u32)ld64a(rep)) ^ exr) & 1u;
                if (__ballot(bad != 0) == 0ULL) break;
                if (++guard > GUARD_MAX) break;
                __builtin_amdgcn_s_sleep(1);
            }
        }
        // ---- combined data sweep: 32 x dwordx4, self-validating ----
        const u64* pb1 = sb1 + (size_t)col * 128 + quad * 2;
        const u64* pb2 = sb2 + (size_t)col * 128 + quad * 2;
        Frag16 B1[16], B2[16];
        for (;;) {
            #pragma unroll
            for (int kc = 0; kc < 16; ++kc) {
                LDX4(B1[kc].x, pb1 + kc * 8);
                LDX4(B2[kc].x, pb2 + kc * 8);
            }
            WAITV0();
            u32 bad = 0;
            #pragma unroll
            for (int kc = 0; kc < 16; ++kc) {
                bad |= ((((u32)B1[kc].q[0]) ^ e1) | (((u32)B1[kc].q[1]) ^ e1)) & 1u;
                bad |= ((((u32)B2[kc].q[0]) ^ e2) | (((u32)B2[kc].q[1]) ^ e2)) & 1u;
            }
            if (__ballot(bad != 0) == 0ULL) break;
            if (++guard > GUARD_MAX) break;
        }
        const int ws = (t + 1) & 1;                 // write slot, both rings
        // ---- layer-0 part: h1[t] = tanh(Whh0*h1[t-1] + wx) ----
        if (t < SEQ) {
            f32x4 aH0 = {0.f, 0.f, 0.f, 0.f}, aH1 = aH0;
            #pragma unroll
            for (int kc = 0; kc < 16; kc += 2) {
                aH0 = __builtin_amdgcn_mfma_f32_16x16x32_f16(A0[kc],     B1[kc].v,     aH0, 0, 0, 0);
                aH1 = __builtin_amdgcn_mfma_f32_16x16x32_f16(A0[kc + 1], B1[kc + 1].v, aH1, 0, 0, 0);
            }
            float hf[4]; u16 hv[4];
            #pragma unroll
            for (int i = 0; i < 4; ++i) {
                float pre = aH0[i] + aH1[i] + bs0[i] + wx[i];
                hf[i] = tanhf(pre); hv[i] = f2h(hf[i]);
            }
            st64a(h1ring + (size_t)ws * BHQ + (size_t)col * 128 + (row0 >> 2),
                  pack_tag(hv, (u32)(((t + 1) >> 1) & 1)));
        }
        // ---- layer-1 part: h2[t-1] = tanh(Whh1*h2[t-2] + Wih1*h1[t-1] + b) ----
        if (t >= 1) {
            f32x4 aS0 = {0.f, 0.f, 0.f, 0.f}, aS1 = aS0, aI0 = aS0, aI1 = aS0;
            #pragma unroll
            for (int kc = 0; kc < 16; kc += 2) {
                aS0 = __builtin_amdgcn_mfma_f32_16x16x32_f16(A1[kc],     B2[kc].v,     aS0, 0, 0, 0);
                aS1 = __builtin_amdgcn_mfma_f32_16x16x32_f16(A1[kc + 1], B2[kc + 1].v, aS1, 0, 0, 0);
                aI0 = __builtin_amdgcn_mfma_f32_16x16x32_f16(Aw[kc],     B1[kc].v,     aI0, 0, 0, 0);
                aI1 = __builtin_amdgcn_mfma_f32_16x16x32_f16(Aw[kc + 1], B1[kc + 1].v, aI1, 0, 0, 0);
            }
            float hf[4]; u16 hv[4];
            #pragma unroll
            for (int i = 0; i < 4; ++i) {
                float pre = aS0[i] + aS1[i] + aI0[i] + aI1[i] + bs1[i];
                hf[i] = tanhf(pre); hv[i] = f2h(hf[i]);
            }
            if (t < SEQ)
                st64a(h2ring + (size_t)ws * BHQ + (size_t)col * 128 + (row0 >> 2),
                      pack_tag(hv, (u32)(((t + 3) >> 1) & 1)));
            else
                *(f32x4*)(h2final + col * HD + row0) = *(f32x4*)hf;  // h2[511], f32
        }
    }
}

__global__ __launch_bounds__(256) void out_kernel(
    const float* __restrict__ h2last, const float* __restrict__ Wout,
    const float* __restrict__ bout, float* __restrict__ out)
{
    int o = blockIdx.x * 256 + threadIdx.x;
    int b = blockIdx.y;
    if (o >= OUTD) return;
    const float* hrow = h2last + b * HD;
    const float* wrow = Wout + o * HD;
    float acc = 0.f;
    for (int k = 0; k < HD; k += 4) {
        float4 hv = *(const float4*)(hrow + k);
        float4 wv = *(const float4*)(wrow + k);
        acc += hv.x * wv.x + hv.y * wv.y + hv.z * wv.z + hv.w * wv.w;
    }
    out[b * OUTD + o] = acc + bout[o];
}

extern "C" void kernel_launch(void* const* d_in, const int* in_sizes, int n_in,
                              void* d_out, int out_size, void* d_ws, size_t ws_size,
                              hipStream_t stream) {
    const int*   x     = (const int*)d_in[0];
    const float* W_ih0 = (const float*)d_in[1];
    const float* W_hh0 = (const float*)d_in[2];
    const float* b_ih0 = (const float*)d_in[3];
    const float* b_hh0 = (const float*)d_in[4];
    const float* W_ih1 = (const float*)d_in[5];
    const float* W_hh1 = (const float*)d_in[6];
    const float* b_ih1 = (const float*)d_in[7];
    const float* b_hh1 = (const float*)d_in[8];
    const float* W_out = (const float*)d_in[9];
    const float* b_out = (const float*)d_in[10];

    // ws: hdr 16KB | h1ring 2*64KB | h2ring 2*64KB | h2final 128KB = 409600 B
    const size_t needed = (size_t)HDR_INTS * 4 + 4ULL * BHQ * 8 + (size_t)BH * 4;
    if (ws_size < needed) return;  // signature: absmax=0.149 non-NaN => ws short

    int* hdr = (int*)d_ws;
    u64* h1ring = (u64*)((char*)d_ws + (size_t)HDR_INTS * 4);
    u64* h2ring = h1ring + 2ULL * BHQ;
    float* h2final = (float*)(h2ring + 2ULL * BHQ);

    const long ninit = HDR_INTS + 4L * BHQ;  // 36864
    init_kernel<<<(int)((ninit + 255) / 256), 256, 0, stream>>>(hdr, h1ring, h2ring, x);
    rnn_fused<<<128, 64, 0, stream>>>(W_hh0, W_ih0, x, b_ih0, b_hh0,
                                      W_hh1, W_ih1, b_ih1, b_hh1,
                                      h1ring, h2ring, h2final, hdr);
    out_kernel<<<dim3(4, BATCH), 256, 0, stream>>>(h2final, W_out, b_out, (float*)d_out);
}

// Round 11
// 1811.745 us; speedup vs baseline: 5.0429x; 1.0161x over previous
//
#include <hip/hip_runtime.h>

// 2-layer tanh RNN, B=64 T=512 H=512, f32 in/out.
// R18 = R16 (merged layers, depth-2 self-safe tag rings, PROVEN single-sample
// rep poll WITH s_sleep backoff) + fast_tanh + FUSED 6-chain MFMA compute.
// R17 post-mortem: the 2-deep no-backoff pipelined poll tripwired — max-rate
// coherent reads from 128 waves starve producer stores at the coherence
// point; one wave exhausts the cumulative guard, then publishes validly-
// tagged garbage -> run-to-run divergent corruption. Lessons: poll rate has
// a stability cliff (always back off); never remove s_sleep from spins.
// R18's compute fusion: R16 serialized sweep -> 16 MFMA -> tanh -> store h1
// -> 32 MFMA -> tanh -> store h2, so the h2 store (consumed by the SAME
// next-step sweep as h1's) landed ~0.3us late. Now all 48 MFMAs issue as 6
// independent interleaved chains, both tanh+stores back-to-back; edge steps
// compute unconditionally and guard only the stores (t=0 poison B2 is
// denormal ~0 -> finite tanh -> discarded). fast_tanh = (e^2x-1)/(e^2x+1),
// clamp +-9, err ~1e-7 << f16 quantization.
// Chain model (fits R9..R16): step ~= propagate + detect(1.5RTT) + sweep(RTT)
// + compute/store + 0.028us*coherent_ops_per_CU. R16 = 3.44us/step @ ~35
// ops/CU. If R18 lands ~=R16, compute is off the critical chain and the
// remaining floor is structural fabric latency (declare roofline).
// History (us/step): R7 8.94 | R8 13.5 | R9 8.98 | R10 fail | R11 17.5 |
// R12 5.55 | R13 fail | R14 fail | R15 3.91 | R16 3.44 | R17 tripwire.

#define HD 512
#define BATCH 64
#define SEQ 512
#define NVOCAB 25
#define OUTD 1000
#define BH (BATCH * HD)   // 32768 u16 per ring slot
#define BHQ (BH / 4)      // 8192 u64 per ring slot
#define IS64_OFF 2048
#define HDR_INTS 4096
#define GUARD_MAX (1L << 23)  // spin budget (drain storms, fail-fast on bug)

typedef unsigned short u16;
typedef unsigned int u32;
typedef unsigned long long u64;
typedef __attribute__((ext_vector_type(8))) _Float16 half8;   // 8 f16 = 16B
typedef __attribute__((ext_vector_type(4))) u32 u32x4;        // 16B
typedef __attribute__((ext_vector_type(4))) float f32x4;

union Frag16 { u32x4 x; u64 q[2]; u16 h[8]; half8 v; };

__device__ __forceinline__ u16 f2h(float f) {
    union { _Float16 h; u16 u; } c; c.h = (_Float16)f; return c.u;  // RNE
}
__device__ __forceinline__ u64 ld64a(const u64* p) {
    return __hip_atomic_load((u64*)p, __ATOMIC_RELAXED, __HIP_MEMORY_SCOPE_AGENT);
}
__device__ __forceinline__ void st64a(u64* p, u64 v) {
    __hip_atomic_store(p, v, __ATOMIC_RELAXED, __HIP_MEMORY_SCOPE_AGENT);
}
// 16B device-coherent load, computed address (R12/R15/R16-proven form).
// Non-atomic OK: each 8B half carries its own tag and self-validates.
#define LDX4(dst, addr) \
    asm volatile("global_load_dwordx4 %0, %1, off sc0" : "=v"(dst) : "v"(addr))
#define WAITV0() do { \
    asm volatile("s_waitcnt vmcnt(0)" ::: "memory"); \
    __builtin_amdgcn_sched_barrier(0); \
} while (0)

__device__ __forceinline__ u64 pack_tag(const u16 hv[4], u32 tag) {
    return ((u64)(((u32)hv[0] & 0xFFFEu) | tag))
         | ((u64)hv[1] << 16) | ((u64)hv[2] << 32) | ((u64)hv[3] << 48);
}

// fast tanh: (e^{2x}-1)/(e^{2x}+1), clamp +-9 (tanh(9)=1-2e-8; e^18 finite).
// __expf -> v_exp_f32 path, __fdividef -> rcp+mul. Err ~1e-7 << f16 ulp.
__device__ __forceinline__ float fast_tanh(float x) {
    float xc = fminf(fmaxf(x, -9.0f), 9.0f);
    float E = __expf(xc + xc);
    return __fdividef(E - 1.0f, E + 1.0f);
}

// hdr ints: is64 @ [2048] (rest unused). Rings (u64 space after hdr):
// h1[2*BHQ]: slot0 = 0 (valid h1[0]=0, tag 0), slot1 = 1 (poison tag 1);
// h2[2*BHQ]: slot0 = 1 (poison for h2[-2] read: expect tag 1, data~0, VALID
//            as h2[-2]=0), slot1 = 1 (valid h2[-1]=0, tag 1).
__global__ void init_kernel(int* hdr, u64* h1, u64* h2, const int* x32) {
    long i = (long)blockIdx.x * 256 + threadIdx.x;
    if (i < HDR_INTS) {
        if (i == IS64_OFF) {  // probe x int width: int64 LE => odd words all 0
            int all0 = 1;
            for (int j = 0; j < 64; ++j) if (x32[2 * j + 1] != 0) all0 = 0;
            hdr[i] = all0;
        } else hdr[i] = 0;
    } else {
        long r = i - HDR_INTS;
        if (r < 2L * BHQ) h1[r] = (r < BHQ) ? 0ull : 1ull;
        else if (r < 4L * BHQ) h2[r - 2L * BHQ] = 1ull;
    }
}

__global__ __launch_bounds__(64, 1) void rnn_fused(
    const float* __restrict__ Whh0, const float* __restrict__ Wih0,
    const int* __restrict__ x,
    const float* __restrict__ bih0, const float* __restrict__ bhh0,
    const float* __restrict__ Whh1, const float* __restrict__ Wih1,
    const float* __restrict__ bih1, const float* __restrict__ bhh1,
    u64* h1ring, u64* h2ring, float* h2final, int* hdr)
{
    const int lane = threadIdx.x & 63;
    const int quad = lane >> 4;
    const int l16  = lane & 15;
    const int u    = (int)blockIdx.x >> 2;      // row-unit 0..31 (16 rows)
    const int cg   = (int)blockIdx.x & 3;       // col-group 0..3 (16 cols)
    const int rowbase = u * 16;
    const int arow = rowbase + l16;             // A row (m = lane&15)
    const int row0 = rowbase + quad * 4;        // C/D rows: quad*4 + reg
    const int col  = cg * 16 + l16;             // C/D col (batch)
    // rep packet of producer unit pg (32 row-units of my cg domain): one 8B
    // packet at col cg*16+(pg&15), u64 idx pg*4+(pg&3) (row pg*16+4*(pg&3)).
    const int pg = lane & 31;
    const size_t repoff = (size_t)(cg * 16 + (pg & 15)) * 128 + pg * 4 + (pg & 3);

    // Three weight sets, f16 frags, register-resident:
    // A[m=lane&15][k=kc*32+quad*8+j], 64 VGPRs each.
    half8 A0[16], A1[16], Aw[16];
    #pragma unroll
    for (int kc = 0; kc < 16; ++kc) {
        Frag16 t0, t1, tw;
        #pragma unroll
        for (int j = 0; j < 8; ++j) {
            const int widx = arow * HD + kc * 32 + quad * 8 + j;
            t0.h[j] = f2h(Whh0[widx]);
            t1.h[j] = f2h(Whh1[widx]);
            tw.h[j] = f2h(Wih1[widx]);
        }
        A0[kc] = t0.v; A1[kc] = t1.v; Aw[kc] = tw.v;
    }
    float bs0[4], bs1[4];
    #pragma unroll
    for (int i = 0; i < 4; ++i) {
        bs0[i] = bih0[row0 + i] + bhh0[row0 + i];
        bs1[i] = bih1[row0 + i] + bhh1[row0 + i];
    }
    const int is64 = hdr[IS64_OFF];

    long guard = 0;

    for (int t = 0; t <= SEQ; ++t) {
        // x gather + embed row prefetch (read-only, cached); issued before
        // the poll so it's in flight during the wait. tt clamps the epilogue.
        const int tt = (t < SEQ) ? t : (SEQ - 1);
        int xi = is64 ? (int)((const long long*)x)[col * SEQ + tt]
                      : x[col * SEQ + tt];
        float wx[4];
        #pragma unroll
        for (int i = 0; i < 4; ++i) wx[i] = Wih0[(row0 + i) * NVOCAB + xi];

        const int rs = t & 1;                       // read slot, both rings
        const u32 e1 = (u32)((t >> 1) & 1);         // h1[t-1] state tag
        const u32 e2 = (u32)(((t + 2) >> 1) & 1);   // h2[t-2] state tag
        const u64* sb1 = h1ring + (size_t)rs * BHQ;
        const u64* sb2 = h2ring + (size_t)rs * BHQ;
        // ---- rep poll (R16-proven: single sample + s_sleep backoff).
        // Lanes 0-31 watch h1 producers, lanes 32-63 watch h2 producers.
        {
            const u64* rep = (lane < 32) ? (sb1 + repoff) : (sb2 + repoff);
            const u32 exr = (lane < 32) ? e1 : e2;
            for (;;) {
                u32 bad = (((u32)ld64a(rep)) ^ exr) & 1u;
                if (__ballot(bad != 0) == 0ULL) break;
                if (++guard > GUARD_MAX) break;
                __builtin_amdgcn_s_sleep(1);
            }
        }
        // ---- combined data sweep: 32 x dwordx4, self-validating ----
        const u64* pb1 = sb1 + (size_t)col * 128 + quad * 2;
        const u64* pb2 = sb2 + (size_t)col * 128 + quad * 2;
        Frag16 B1[16], B2[16];
        for (;;) {
            #pragma unroll
            for (int kc = 0; kc < 16; ++kc) {
                LDX4(B1[kc].x, pb1 + kc * 8);
                LDX4(B2[kc].x, pb2 + kc * 8);
            }
            WAITV0();
            u32 bad = 0;
            #pragma unroll
            for (int kc = 0; kc < 16; ++kc) {
                bad |= ((((u32)B1[kc].q[0]) ^ e1) | (((u32)B1[kc].q[1]) ^ e1)) & 1u;
                bad |= ((((u32)B2[kc].q[0]) ^ e2) | (((u32)B2[kc].q[1]) ^ e2)) & 1u;
            }
            if (__ballot(bad != 0) == 0ULL) break;
            if (++guard > GUARD_MAX) break;
        }
        // ---- FUSED compute: 48 MFMAs as 6 independent interleaved chains.
        // L0: h1[t] = tanh(Whh0*h1[t-1] + wx);  L1: h2[t-1] = tanh(Whh1*
        // h2[t-2] + Wih1*h1[t-1] + b). Unconditional; stores guarded below.
        f32x4 aH0 = {0.f, 0.f, 0.f, 0.f}, aH1 = aH0;
        f32x4 aS0 = aH0, aS1 = aH0, aI0 = aH0, aI1 = aH0;
        #pragma unroll
        for (int kc = 0; kc < 16; kc += 2) {
            aH0 = __builtin_amdgcn_mfma_f32_16x16x32_f16(A0[kc],     B1[kc].v,     aH0, 0, 0, 0);
            aS0 = __builtin_amdgcn_mfma_f32_16x16x32_f16(A1[kc],     B2[kc].v,     aS0, 0, 0, 0);
            aI0 = __builtin_amdgcn_mfma_f32_16x16x32_f16(Aw[kc],     B1[kc].v,     aI0, 0, 0, 0);
            aH1 = __builtin_amdgcn_mfma_f32_16x16x32_f16(A0[kc + 1], B1[kc + 1].v, aH1, 0, 0, 0);
            aS1 = __builtin_amdgcn_mfma_f32_16x16x32_f16(A1[kc + 1], B2[kc + 1].v, aS1, 0, 0, 0);
            aI1 = __builtin_amdgcn_mfma_f32_16x16x32_f16(Aw[kc + 1], B1[kc + 1].v, aI1, 0, 0, 0);
        }
        float h0f[4], h1f[4]; u16 h0v[4], h1v[4];
        #pragma unroll
        for (int i = 0; i < 4; ++i) {
            h0f[i] = fast_tanh(aH0[i] + aH1[i] + bs0[i] + wx[i]);
            h0v[i] = f2h(h0f[i]);
            h1f[i] = fast_tanh(aS0[i] + aS1[i] + aI0[i] + aI1[i] + bs1[i]);
            h1v[i] = f2h(h1f[i]);
        }
        const int ws = (t + 1) & 1;                 // write slot, both rings
        const size_t po = (size_t)col * 128 + (row0 >> 2);
        if (t < SEQ) {
            st64a(h1ring + (size_t)ws * BHQ + po,
                  pack_tag(h0v, (u32)(((t + 1) >> 1) & 1)));
            if (t >= 1)
                st64a(h2ring + (size_t)ws * BHQ + po,
                      pack_tag(h1v, (u32)(((t + 3) >> 1) & 1)));
        } else {
            *(f32x4*)(h2final + col * HD + row0) = *(f32x4*)h1f;  // h2[511], f32
        }
    }
}

__global__ __launch_bounds__(256) void out_kernel(
    const float* __restrict__ h2last, const float* __restrict__ Wout,
    const float* __restrict__ bout, float* __restrict__ out)
{
    int o = blockIdx.x * 256 + threadIdx.x;
    int b = blockIdx.y;
    if (o >= OUTD) return;
    const float* hrow = h2last + b * HD;
    const float* wrow = Wout + o * HD;
    float acc = 0.f;
    for (int k = 0; k < HD; k += 4) {
        float4 hv = *(const float4*)(hrow + k);
        float4 wv = *(const float4*)(wrow + k);
        acc += hv.x * wv.x + hv.y * wv.y + hv.z * wv.z + hv.w * wv.w;
    }
    out[b * OUTD + o] = acc + bout[o];
}

extern "C" void kernel_launch(void* const* d_in, const int* in_sizes, int n_in,
                              void* d_out, int out_size, void* d_ws, size_t ws_size,
                              hipStream_t stream) {
    const int*   x     = (const int*)d_in[0];
    const float* W_ih0 = (const float*)d_in[1];
    const float* W_hh0 = (const float*)d_in[2];
    const float* b_ih0 = (const float*)d_in[3];
    const float* b_hh0 = (const float*)d_in[4];
    const float* W_ih1 = (const float*)d_in[5];
    const float* W_hh1 = (const float*)d_in[6];
    const float* b_ih1 = (const float*)d_in[7];
    const float* b_hh1 = (const float*)d_in[8];
    const float* W_out = (const float*)d_in[9];
    const float* b_out = (const float*)d_in[10];

    // ws: hdr 16KB | h1ring 2*64KB | h2ring 2*64KB | h2final 128KB = 409600 B
    const size_t needed = (size_t)HDR_INTS * 4 + 4ULL * BHQ * 8 + (size_t)BH * 4;
    if (ws_size < needed) return;  // signature: absmax=0.149 non-NaN => ws short

    int* hdr = (int*)d_ws;
    u64* h1ring = (u64*)((char*)d_ws + (size_t)HDR_INTS * 4);
    u64* h2ring = h1ring + 2ULL * BHQ;
    float* h2final = (float*)(h2ring + 2ULL * BHQ);

    const long ninit = HDR_INTS + 4L * BHQ;  // 36864
    init_kernel<<<(int)((ninit + 255) / 256), 256, 0, stream>>>(hdr, h1ring, h2ring, x);
    rnn_fused<<<128, 64, 0, stream>>>(W_hh0, W_ih0, x, b_ih0, b_hh0,
                                      W_hh1, W_ih1, b_ih1, b_hh1,
                                      h1ring, h2ring, h2final, hdr);
    out_kernel<<<dim3(4, BATCH), 256, 0, stream>>>(h2final, W_out, b_out, (float*)d_out);
}